// Round 5
// baseline (1321.701 us; speedup 1.0000x reference)
//
#include <hip/hip_runtime.h>

typedef __attribute__((ext_vector_type(8))) short short8;
typedef __attribute__((ext_vector_type(4))) float f32x4;

#define MFMA16(a, b, c) __builtin_amdgcn_mfma_f32_16x16x32_bf16((a), (b), (c), 0, 0, 0)

constexpr int Bv  = 32;    // batch
constexpr int Lv  = 168;   // encoder length
constexpr int Sv  = 512;   // sites
constexpr int HZv = 24;    // horizon
constexpr int HSTR = 72;   // LDS h-row stride in shorts: 64 units + 8 pad (144 B/row)
constexpr int HBUF = 32 * HSTR;

__device__ __forceinline__ float b2f(short s) {
    unsigned u = ((unsigned)(unsigned short)s) << 16;
    return __builtin_bit_cast(float, u);
}
__device__ __forceinline__ short f2b(float f) {
    unsigned u = __builtin_bit_cast(unsigned, f);
    unsigned r = (u + 0x7FFFu + ((u >> 16) & 1u)) >> 16;   // RNE
    return (short)(unsigned short)r;
}
__device__ __forceinline__ float sigm(float x) {
    x = fmaxf(x, -85.0f);
    float e = __builtin_amdgcn_exp2f(-1.44269504088896f * x);
    return __builtin_amdgcn_rcpf(1.0f + e);
}
__device__ __forceinline__ float tanh_(float x) {
    x = fminf(x, 43.0f);
    float e = __builtin_amdgcn_exp2f(2.88539008177793f * x); // exp(2x)
    return 1.0f - 2.0f * __builtin_amdgcn_rcpf(e + 1.0f);
}
// load 8 consecutive f32, keep bf16 hi parts only (per-lane register fragments)
__device__ __forceinline__ void hi8(const float* __restrict__ p, short8& hi) {
#pragma unroll
    for (int j = 0; j < 8; ++j) hi[j] = f2b(p[j]);
}

__global__ __launch_bounds__(256, 1)
void sitewise_lstm(const float* __restrict__ x_seq,
                   const float* __restrict__ Wih0, const float* __restrict__ Whh0,
                   const float* __restrict__ bih0, const float* __restrict__ bhh0,
                   const float* __restrict__ Wih1, const float* __restrict__ Whh1,
                   const float* __restrict__ bih1, const float* __restrict__ bhh1,
                   const float* __restrict__ Wcih, const float* __restrict__ Wchh,
                   const float* __restrict__ bcih, const float* __restrict__ bchh,
                   const float* __restrict__ Wout, const float* __restrict__ bout,
                   float* __restrict__ out)
{
    __shared__ __align__(16) short WloL[3 * 16384];  // bf16 lo residuals, fragment-ordered
    __shared__ __align__(16) short Hhi[4 * HBUF];    // h state hi, [layer*2+parity]
    __shared__ __align__(16) short Hlo[4 * HBUF];    // h state lo
    __shared__ float woutF[64];
    __shared__ float ybufF[32];

    const int tid  = threadIdx.x;
    const int w    = tid >> 6;        // wave 0..3 owns gate cols u in [16w, 16w+16)
    const int lane = tid & 63;
    const int q    = lane >> 4;
    const int col  = lane & 15;
    const int bid  = blockIdx.x;
    const int b    = bid >> 4;
    const int s0   = (bid & 15) << 5;
    const int uu   = w * 16 + col;    // this lane's hidden-unit column

    for (int i = tid; i < 4 * HBUF / 2; i += 256) { ((int*)Hhi)[i] = 0; ((int*)Hlo)[i] = 0; }
    if (tid < 64) woutF[tid] = Wout[tid];

    // ---- cooperative: stage W_lo residuals into LDS (fragment order) ----
    // fr = w*512 + g*128 + kc*64 + q*16 + col ; element jj -> W[g*64+w*16+col][kc*32+q*8+jj]
    for (int idx = tid; idx < 3 * 2048; idx += 256) {
        const int m  = idx >> 11, fr = idx & 2047;
        const int fcol = fr & 15, fq = (fr >> 4) & 3, fkc = (fr >> 6) & 1;
        const int fg = (fr >> 7) & 3, fw = fr >> 9;
        const float* W = (m == 0) ? Whh0 : (m == 1) ? Wih1 : Whh1;
        const float* p = W + (fg * 64 + fw * 16 + fcol) * 64 + fkc * 32 + fq * 8;
        short8 lv;
#pragma unroll
        for (int jj = 0; jj < 8; ++jj) {
            float x = p[jj];
            lv[jj] = f2b(x - b2f(f2b(x)));
        }
        *(short8*)(WloL + m * 16384 + fr * 8) = lv;
    }

    // ---- per-lane: W_hi fragments in registers ----
    short8 Whi[3][4][2];   // [Whh0, Wih1, Whh1][g][kc]; slot 0 reused for Wchh in decoder
    int frOff[4][2];
    float bias0[4], bias1[4], biasc[4], wih0g[4], wcihg[4];
#pragma unroll
    for (int g = 0; g < 4; ++g) {
        const int j = g * 64 + uu;
        bias0[g] = bih0[j] + bhh0[j];
        bias1[g] = bih1[j] + bhh1[j];
        biasc[g] = bcih[j] + bchh[j];
        wih0g[g] = Wih0[j];
        wcihg[g] = Wcih[j];
#pragma unroll
        for (int kc = 0; kc < 2; ++kc) {
            const int off = j * 64 + kc * 32 + q * 8;   // W[j][k0..k0+7]
            frOff[g][kc] = ((((w * 4 + g) * 2 + kc) * 4 + q) * 16 + col) * 8;
            hi8(Whh0 + off, Whi[0][g][kc]);
            hi8(Wih1 + off, Whi[1][g][kc]);
            hi8(Whh1 + off, Whi[2][g][kc]);
        }
    }

    float c0[8], c1[8];
#pragma unroll
    for (int i = 0; i < 8; ++i) { c0[i] = 0.f; c1[i] = 0.f; }

    const float* xbF = x_seq + b * Lv * Sv + s0;
    __syncthreads();

    // ================= encoder: 2 fused LSTM layers =================
    for (int t = 0; t < Lv; ++t) {
        const int p = t & 1, np = p ^ 1;
        const int B0p = p * HBUF, B0n = np * HBUF;
        const int B1p = (2 + p) * HBUF, B1n = (2 + np) * HBUF;

        f32x4 xv[2];
#pragma unroll
        for (int mt = 0; mt < 2; ++mt)
            xv[mt] = *(const f32x4*)(xbF + t * Sv + mt * 16 + q * 4);

        // ---- layer 0: G = (h0_hi + h0_lo) @ (Whh0_hi + dW)^T ----
        short8 ah[2][2], al[2][2], a1h[2][2], a1l[2][2];
#pragma unroll
        for (int kc = 0; kc < 2; ++kc)
#pragma unroll
            for (int mt = 0; mt < 2; ++mt) {
                const int ro = (mt * 16 + col) * HSTR + kc * 32 + q * 8;
                ah[kc][mt]  = *(const short8*)(Hhi + B0p + ro);
                al[kc][mt]  = *(const short8*)(Hlo + B0p + ro);
                a1h[kc][mt] = *(const short8*)(Hhi + B1p + ro);
                a1l[kc][mt] = *(const short8*)(Hlo + B1p + ro);
            }
        f32x4 pre[4][2];
#pragma unroll
        for (int g = 0; g < 4; ++g) {
            const short8 d0 = *(const short8*)(WloL + frOff[g][0]);
            const short8 d1 = *(const short8*)(WloL + frOff[g][1]);
#pragma unroll
            for (int mt = 0; mt < 2; ++mt) {
                f32x4 a = {bias0[g], bias0[g], bias0[g], bias0[g]};
                a = MFMA16(ah[0][mt], Whi[0][g][0], a);
                a = MFMA16(ah[1][mt], Whi[0][g][1], a);
                a = MFMA16(al[0][mt], Whi[0][g][0], a);
                a = MFMA16(al[1][mt], Whi[0][g][1], a);
                a = MFMA16(ah[0][mt], d0, a);
                a = MFMA16(ah[1][mt], d1, a);
                pre[g][mt] = a;
            }
        }
#pragma unroll
        for (int mt = 0; mt < 2; ++mt)
#pragma unroll
            for (int r = 0; r < 4; ++r) {
                const float xw = xv[mt][r];
                const float ig = sigm (pre[0][mt][r] + xw * wih0g[0]);
                const float fg = sigm (pre[1][mt][r] + xw * wih0g[1]);
                const float gt = tanh_(pre[2][mt][r] + xw * wih0g[2]);
                const float og = sigm (pre[3][mt][r] + xw * wih0g[3]);
                const float c  = fg * c0[mt * 4 + r] + ig * gt;
                c0[mt * 4 + r] = c;
                const float h  = og * tanh_(c);
                const short hb = f2b(h);
                const int  wi  = B0n + (mt * 16 + q * 4 + r) * HSTR + uu;
                Hhi[wi] = hb;
                Hlo[wi] = f2b(h - b2f(hb));
            }
        __syncthreads();   // h0(new) visible

        // ---- layer 1: G = h0new @ Wih1^T + h1 @ Whh1^T ----
        short8 bh[2][2], bl[2][2];
#pragma unroll
        for (int kc = 0; kc < 2; ++kc)
#pragma unroll
            for (int mt = 0; mt < 2; ++mt) {
                const int ro = (mt * 16 + col) * HSTR + kc * 32 + q * 8;
                bh[kc][mt] = *(const short8*)(Hhi + B0n + ro);
                bl[kc][mt] = *(const short8*)(Hlo + B0n + ro);
            }
#pragma unroll
        for (int g = 0; g < 4; ++g) {
            const short8 di0 = *(const short8*)(WloL + 16384 + frOff[g][0]);
            const short8 di1 = *(const short8*)(WloL + 16384 + frOff[g][1]);
            const short8 dh0 = *(const short8*)(WloL + 32768 + frOff[g][0]);
            const short8 dh1 = *(const short8*)(WloL + 32768 + frOff[g][1]);
#pragma unroll
            for (int mt = 0; mt < 2; ++mt) {
                f32x4 a = {bias1[g], bias1[g], bias1[g], bias1[g]};
                a = MFMA16(bh[0][mt], Whi[1][g][0], a);
                a = MFMA16(bh[1][mt], Whi[1][g][1], a);
                a = MFMA16(bl[0][mt], Whi[1][g][0], a);
                a = MFMA16(bl[1][mt], Whi[1][g][1], a);
                a = MFMA16(bh[0][mt], di0, a);
                a = MFMA16(bh[1][mt], di1, a);
                a = MFMA16(a1h[0][mt], Whi[2][g][0], a);
                a = MFMA16(a1h[1][mt], Whi[2][g][1], a);
                a = MFMA16(a1l[0][mt], Whi[2][g][0], a);
                a = MFMA16(a1l[1][mt], Whi[2][g][1], a);
                a = MFMA16(a1h[0][mt], dh0, a);
                a = MFMA16(a1h[1][mt], dh1, a);
                pre[g][mt] = a;
            }
        }
#pragma unroll
        for (int mt = 0; mt < 2; ++mt)
#pragma unroll
            for (int r = 0; r < 4; ++r) {
                const float ig = sigm (pre[0][mt][r]);
                const float fg = sigm (pre[1][mt][r]);
                const float gt = tanh_(pre[2][mt][r]);
                const float og = sigm (pre[3][mt][r]);
                const float c  = fg * c1[mt * 4 + r] + ig * gt;
                c1[mt * 4 + r] = c;
                const float h  = og * tanh_(c);
                const short hb = f2b(h);
                const int  wi  = B1n + (mt * 16 + q * 4 + r) * HSTR + uu;
                Hhi[wi] = hb;
                Hlo[wi] = f2b(h - b2f(hb));
            }
        __syncthreads();   // state visible for next step
    }

    // ================= decoder: 24 autoregressive steps =================
    // re-stage Wchh lo into slot 0 (encoder's final barrier guarantees no readers)
    for (int idx = tid; idx < 2048; idx += 256) {
        const int fr = idx;
        const int fcol = fr & 15, fq = (fr >> 4) & 3, fkc = (fr >> 6) & 1;
        const int fg = (fr >> 7) & 3, fw = fr >> 9;
        const float* p = Wchh + (fg * 64 + fw * 16 + fcol) * 64 + fkc * 32 + fq * 8;
        short8 lv;
#pragma unroll
        for (int jj = 0; jj < 8; ++jj) {
            float x = p[jj];
            lv[jj] = f2b(x - b2f(f2b(x)));
        }
        *(short8*)(WloL + fr * 8) = lv;
    }
#pragma unroll
    for (int g = 0; g < 4; ++g)
#pragma unroll
        for (int kc = 0; kc < 2; ++kc)
            hi8(Wchh + (g * 64 + uu) * 64 + kc * 32 + q * 8, Whi[0][g][kc]);
    if (tid < 32) ybufF[tid] = xbF[(Lv - 1) * Sv + tid];   // x_cur
    __syncthreads();

    const float boutF = bout[0];
    float* outp = out + b * HZv * Sv + s0;

    for (int t = 0; t < HZv; ++t) {
        const int p = t & 1, np = p ^ 1;
        const int B1p = (2 + p) * HBUF, B1n = (2 + np) * HBUF;

        short8 ah[2][2], al[2][2];
#pragma unroll
        for (int kc = 0; kc < 2; ++kc)
#pragma unroll
            for (int mt = 0; mt < 2; ++mt) {
                const int o = B1p + (mt * 16 + col) * HSTR + kc * 32 + q * 8;
                ah[kc][mt] = *(const short8*)(Hhi + o);
                al[kc][mt] = *(const short8*)(Hlo + o);
            }
        float yv[2][4];
#pragma unroll
        for (int mt = 0; mt < 2; ++mt)
#pragma unroll
            for (int r = 0; r < 4; ++r)
                yv[mt][r] = ybufF[mt * 16 + q * 4 + r];

        f32x4 pre[4][2];
#pragma unroll
        for (int g = 0; g < 4; ++g) {
            const short8 d0 = *(const short8*)(WloL + frOff[g][0]);
            const short8 d1 = *(const short8*)(WloL + frOff[g][1]);
#pragma unroll
            for (int mt = 0; mt < 2; ++mt) {
                f32x4 a = {biasc[g], biasc[g], biasc[g], biasc[g]};
                a = MFMA16(ah[0][mt], Whi[0][g][0], a);
                a = MFMA16(ah[1][mt], Whi[0][g][1], a);
                a = MFMA16(al[0][mt], Whi[0][g][0], a);
                a = MFMA16(al[1][mt], Whi[0][g][1], a);
                a = MFMA16(ah[0][mt], d0, a);
                a = MFMA16(ah[1][mt], d1, a);
                pre[g][mt] = a;
            }
        }
#pragma unroll
        for (int mt = 0; mt < 2; ++mt)
#pragma unroll
            for (int r = 0; r < 4; ++r) {
                const float xw = yv[mt][r];
                const float ig = sigm (pre[0][mt][r] + xw * wcihg[0]);
                const float fg = sigm (pre[1][mt][r] + xw * wcihg[1]);
                const float gt = tanh_(pre[2][mt][r] + xw * wcihg[2]);
                const float og = sigm (pre[3][mt][r] + xw * wcihg[3]);
                const float c  = fg * c1[mt * 4 + r] + ig * gt;
                c1[mt * 4 + r] = c;
                const float h  = og * tanh_(c);
                const short hb = f2b(h);
                const int  wi  = B1n + (mt * 16 + q * 4 + r) * HSTR + uu;
                Hhi[wi] = hb;
                Hlo[wi] = f2b(h - b2f(hb));
            }
        __syncthreads();   // h(new) visible

        if (tid < 32) {    // y = h @ W_out^T + b_out (exact f32 from hi+lo)
            const int m = tid;
            float s = boutF;
#pragma unroll
            for (int k = 0; k < 64; ++k)
                s += (b2f(Hhi[B1n + m * HSTR + k]) + b2f(Hlo[B1n + m * HSTR + k])) * woutF[k];
            outp[t * Sv + m] = s;
            ybufF[m] = s;
        }
        __syncthreads();
    }
}

extern "C" void kernel_launch(void* const* d_in, const int* in_sizes, int n_in,
                              void* d_out, int out_size, void* d_ws, size_t ws_size,
                              hipStream_t stream)
{
    const float* x_seq = (const float*)d_in[0];
    const float* Wih0  = (const float*)d_in[1];
    const float* Whh0  = (const float*)d_in[2];
    const float* bih0  = (const float*)d_in[3];
    const float* bhh0  = (const float*)d_in[4];
    const float* Wih1  = (const float*)d_in[5];
    const float* Whh1  = (const float*)d_in[6];
    const float* bih1  = (const float*)d_in[7];
    const float* bhh1  = (const float*)d_in[8];
    const float* Wcih  = (const float*)d_in[9];
    const float* Wchh  = (const float*)d_in[10];
    const float* bcih  = (const float*)d_in[11];
    const float* bchh  = (const float*)d_in[12];
    const float* Wout  = (const float*)d_in[13];
    const float* bout  = (const float*)d_in[14];
    float* out = (float*)d_out;

    hipLaunchKernelGGL(sitewise_lstm, dim3(Bv * (Sv / 32)), dim3(256), 0, stream,
                       x_seq, Wih0, Whh0, bih0, bhh0, Wih1, Whh1, bih1, bhh1,
                       Wcih, Wchh, bcih, bchh, Wout, bout, out);
}

// Round 6
// 1287.086 us; speedup vs baseline: 1.0269x; 1.0269x over previous
//
#include <hip/hip_runtime.h>

typedef __attribute__((ext_vector_type(8))) short short8;
typedef __attribute__((ext_vector_type(4))) float f32x4;

#define MFMA16(a, b, c) __builtin_amdgcn_mfma_f32_16x16x32_bf16((a), (b), (c), 0, 0, 0)

constexpr int Bv  = 32;    // batch
constexpr int Lv  = 168;   // encoder length
constexpr int Sv  = 512;   // sites
constexpr int HZv = 24;    // horizon
constexpr int HSTR = 72;   // LDS h-row stride in shorts: 64 units + 8 pad (144 B/row)
constexpr int HBUF = 32 * HSTR;

__device__ __forceinline__ float b2f(short s) {
    unsigned u = ((unsigned)(unsigned short)s) << 16;
    return __builtin_bit_cast(float, u);
}
__device__ __forceinline__ short f2b(float f) {
    unsigned u = __builtin_bit_cast(unsigned, f);
    unsigned r = (u + 0x7FFFu + ((u >> 16) & 1u)) >> 16;   // RNE
    return (short)(unsigned short)r;
}
__device__ __forceinline__ float sigm(float x) {
    x = fmaxf(x, -85.0f);
    float e = __builtin_amdgcn_exp2f(-1.44269504088896f * x);
    return __builtin_amdgcn_rcpf(1.0f + e);
}
__device__ __forceinline__ float tanh_(float x) {
    x = fminf(x, 43.0f);
    float e = __builtin_amdgcn_exp2f(2.88539008177793f * x); // exp(2x)
    return 1.0f - 2.0f * __builtin_amdgcn_rcpf(e + 1.0f);
}
__device__ __forceinline__ void hi8(const float* __restrict__ p, short8& hi) {
#pragma unroll
    for (int j = 0; j < 8; ++j) hi[j] = f2b(p[j]);
}

__global__ __launch_bounds__(256, 1)
void sitewise_lstm(const float* __restrict__ x_seq,
                   const float* __restrict__ Wih0, const float* __restrict__ Whh0,
                   const float* __restrict__ bih0, const float* __restrict__ bhh0,
                   const float* __restrict__ Wih1, const float* __restrict__ Whh1,
                   const float* __restrict__ bih1, const float* __restrict__ bhh1,
                   const float* __restrict__ Wcih, const float* __restrict__ Wchh,
                   const float* __restrict__ bcih, const float* __restrict__ bchh,
                   const float* __restrict__ Wout, const float* __restrict__ bout,
                   float* __restrict__ out)
{
    __shared__ __align__(16) short WloL[3 * 16384];  // bf16 lo residuals, fragment-ordered (96 KB)
    __shared__ __align__(16) short Hhi[4 * HBUF];    // h state hi, [layer*2+parity] (18.4 KB)
    __shared__ __align__(16) short Hlo[4 * HBUF];    // h state lo (18.4 KB)
    __shared__ __align__(16) float XL[Lv * 32];      // staged x column (21.5 KB)
    __shared__ float woutF[64];
    __shared__ float ybufF[32];

    const int tid  = threadIdx.x;
    const int w    = tid >> 6;        // wave 0..3 owns gate cols u in [16w, 16w+16)
    const int lane = tid & 63;
    const int q    = lane >> 4;
    const int col  = lane & 15;
    const int bid  = blockIdx.x;
    const int b    = bid >> 4;
    const int s0   = (bid & 15) << 5;
    const int uu   = w * 16 + col;    // this lane's hidden-unit column

    for (int i = tid; i < 4 * HBUF / 2; i += 256) { ((int*)Hhi)[i] = 0; ((int*)Hlo)[i] = 0; }
    if (tid < 64) woutF[tid] = Wout[tid];

    const float* xbF = x_seq + b * Lv * Sv + s0;
    // ---- stage x column into LDS (coalesced 32-lane rows) ----
    for (int idx = tid; idx < Lv * 32; idx += 256)
        XL[idx] = xbF[(idx >> 5) * Sv + (idx & 31)];

    // ---- cooperative: stage W_lo residuals into LDS (fragment order) ----
    for (int idx = tid; idx < 3 * 2048; idx += 256) {
        const int m  = idx >> 11, fr = idx & 2047;
        const int fcol = fr & 15, fq = (fr >> 4) & 3, fkc = (fr >> 6) & 1;
        const int fg = (fr >> 7) & 3, fw = fr >> 9;
        const float* W = (m == 0) ? Whh0 : (m == 1) ? Wih1 : Whh1;
        const float* p = W + (fg * 64 + fw * 16 + fcol) * 64 + fkc * 32 + fq * 8;
        short8 lv;
#pragma unroll
        for (int jj = 0; jj < 8; ++jj) {
            float x = p[jj];
            lv[jj] = f2b(x - b2f(f2b(x)));
        }
        *(short8*)(WloL + m * 16384 + fr * 8) = lv;
    }

    // ---- per-lane: W_hi fragments in registers ----
    short8 Whi[3][4][2];   // [Whh0, Wih1, Whh1][g][kc]; slot 0 reused for Wchh in decoder
    int frOff[4][2];
    float bias0[4], bias1[4], biasc[4], wih0g[4], wcihg[4];
#pragma unroll
    for (int g = 0; g < 4; ++g) {
        const int j = g * 64 + uu;
        bias0[g] = bih0[j] + bhh0[j];
        bias1[g] = bih1[j] + bhh1[j];
        biasc[g] = bcih[j] + bchh[j];
        wih0g[g] = Wih0[j];
        wcihg[g] = Wcih[j];
#pragma unroll
        for (int kc = 0; kc < 2; ++kc) {
            const int off = j * 64 + kc * 32 + q * 8;
            frOff[g][kc] = ((((w * 4 + g) * 2 + kc) * 4 + q) * 16 + col) * 8;
            hi8(Whh0 + off, Whi[0][g][kc]);
            hi8(Wih1 + off, Whi[1][g][kc]);
            hi8(Whh1 + off, Whi[2][g][kc]);
        }
    }

    float c0[8], c1[8];
#pragma unroll
    for (int i = 0; i < 8; ++i) { c0[i] = 0.f; c1[i] = 0.f; }

    __syncthreads();

    // ================= encoder: 2 fused LSTM layers =================
    for (int t = 0; t < Lv; ++t) {
        const int p = t & 1, np = p ^ 1;
        const int B0p = p * HBUF, B0n = np * HBUF;
        const int B1p = (2 + p) * HBUF, B1n = (2 + np) * HBUF;

        // ---- phase A: issue ALL reads up front (x, h frags, Wlo frags) ----
        f32x4 xv[2];
#pragma unroll
        for (int mt = 0; mt < 2; ++mt)
            xv[mt] = *(const f32x4*)(XL + t * 32 + mt * 16 + q * 4);

        short8 ah[2][2], al[2][2], a1h[2][2], a1l[2][2];
#pragma unroll
        for (int kc = 0; kc < 2; ++kc)
#pragma unroll
            for (int mt = 0; mt < 2; ++mt) {
                const int ro = (mt * 16 + col) * HSTR + kc * 32 + q * 8;
                ah[kc][mt]  = *(const short8*)(Hhi + B0p + ro);
                al[kc][mt]  = *(const short8*)(Hlo + B0p + ro);
                a1h[kc][mt] = *(const short8*)(Hhi + B1p + ro);
                a1l[kc][mt] = *(const short8*)(Hlo + B1p + ro);
            }
        short8 dA[4][2];
#pragma unroll
        for (int g = 0; g < 4; ++g) {
            dA[g][0] = *(const short8*)(WloL + frOff[g][0]);
            dA[g][1] = *(const short8*)(WloL + frOff[g][1]);
        }

        // ---- layer 0 MFMA: 8 chains interleaved term-by-term (bit-identical order per chain) ----
        f32x4 pre[4][2];
#pragma unroll
        for (int g = 0; g < 4; ++g)
#pragma unroll
            for (int mt = 0; mt < 2; ++mt)
                pre[g][mt] = (f32x4){bias0[g], bias0[g], bias0[g], bias0[g]};
#pragma unroll
        for (int g = 0; g < 4; ++g)
#pragma unroll
            for (int mt = 0; mt < 2; ++mt) pre[g][mt] = MFMA16(ah[0][mt], Whi[0][g][0], pre[g][mt]);
#pragma unroll
        for (int g = 0; g < 4; ++g)
#pragma unroll
            for (int mt = 0; mt < 2; ++mt) pre[g][mt] = MFMA16(ah[1][mt], Whi[0][g][1], pre[g][mt]);
#pragma unroll
        for (int g = 0; g < 4; ++g)
#pragma unroll
            for (int mt = 0; mt < 2; ++mt) pre[g][mt] = MFMA16(al[0][mt], Whi[0][g][0], pre[g][mt]);
#pragma unroll
        for (int g = 0; g < 4; ++g)
#pragma unroll
            for (int mt = 0; mt < 2; ++mt) pre[g][mt] = MFMA16(al[1][mt], Whi[0][g][1], pre[g][mt]);
#pragma unroll
        for (int g = 0; g < 4; ++g)
#pragma unroll
            for (int mt = 0; mt < 2; ++mt) pre[g][mt] = MFMA16(ah[0][mt], dA[g][0], pre[g][mt]);
#pragma unroll
        for (int g = 0; g < 4; ++g)
#pragma unroll
            for (int mt = 0; mt < 2; ++mt) pre[g][mt] = MFMA16(ah[1][mt], dA[g][1], pre[g][mt]);

#pragma unroll
        for (int mt = 0; mt < 2; ++mt)
#pragma unroll
            for (int r = 0; r < 4; ++r) {
                const float xw = xv[mt][r];
                const float ig = sigm (pre[0][mt][r] + xw * wih0g[0]);
                const float fg = sigm (pre[1][mt][r] + xw * wih0g[1]);
                const float gt = tanh_(pre[2][mt][r] + xw * wih0g[2]);
                const float og = sigm (pre[3][mt][r] + xw * wih0g[3]);
                const float c  = fg * c0[mt * 4 + r] + ig * gt;
                c0[mt * 4 + r] = c;
                const float h  = og * tanh_(c);
                const short hb = f2b(h);
                const int  wi  = B0n + (mt * 16 + q * 4 + r) * HSTR + uu;
                Hhi[wi] = hb;
                Hlo[wi] = f2b(h - b2f(hb));
            }
        __syncthreads();   // h0(new) visible

        // ---- phase B reads: h0new frags + Wih1/Whh1 lo frags ----
        short8 bh[2][2], bl[2][2];
#pragma unroll
        for (int kc = 0; kc < 2; ++kc)
#pragma unroll
            for (int mt = 0; mt < 2; ++mt) {
                const int ro = (mt * 16 + col) * HSTR + kc * 32 + q * 8;
                bh[kc][mt] = *(const short8*)(Hhi + B0n + ro);
                bl[kc][mt] = *(const short8*)(Hlo + B0n + ro);
            }
        short8 dI[4][2], dH[4][2];
#pragma unroll
        for (int g = 0; g < 4; ++g) {
            dI[g][0] = *(const short8*)(WloL + 16384 + frOff[g][0]);
            dI[g][1] = *(const short8*)(WloL + 16384 + frOff[g][1]);
            dH[g][0] = *(const short8*)(WloL + 32768 + frOff[g][0]);
            dH[g][1] = *(const short8*)(WloL + 32768 + frOff[g][1]);
        }

        // ---- layer 1 MFMA: 8 chains, 12 terms, interleaved ----
#pragma unroll
        for (int g = 0; g < 4; ++g)
#pragma unroll
            for (int mt = 0; mt < 2; ++mt)
                pre[g][mt] = (f32x4){bias1[g], bias1[g], bias1[g], bias1[g]};
#pragma unroll
        for (int g = 0; g < 4; ++g)
#pragma unroll
            for (int mt = 0; mt < 2; ++mt) pre[g][mt] = MFMA16(bh[0][mt], Whi[1][g][0], pre[g][mt]);
#pragma unroll
        for (int g = 0; g < 4; ++g)
#pragma unroll
            for (int mt = 0; mt < 2; ++mt) pre[g][mt] = MFMA16(bh[1][mt], Whi[1][g][1], pre[g][mt]);
#pragma unroll
        for (int g = 0; g < 4; ++g)
#pragma unroll
            for (int mt = 0; mt < 2; ++mt) pre[g][mt] = MFMA16(bl[0][mt], Whi[1][g][0], pre[g][mt]);
#pragma unroll
        for (int g = 0; g < 4; ++g)
#pragma unroll
            for (int mt = 0; mt < 2; ++mt) pre[g][mt] = MFMA16(bl[1][mt], Whi[1][g][1], pre[g][mt]);
#pragma unroll
        for (int g = 0; g < 4; ++g)
#pragma unroll
            for (int mt = 0; mt < 2; ++mt) pre[g][mt] = MFMA16(bh[0][mt], dI[g][0], pre[g][mt]);
#pragma unroll
        for (int g = 0; g < 4; ++g)
#pragma unroll
            for (int mt = 0; mt < 2; ++mt) pre[g][mt] = MFMA16(bh[1][mt], dI[g][1], pre[g][mt]);
#pragma unroll
        for (int g = 0; g < 4; ++g)
#pragma unroll
            for (int mt = 0; mt < 2; ++mt) pre[g][mt] = MFMA16(a1h[0][mt], Whi[2][g][0], pre[g][mt]);
#pragma unroll
        for (int g = 0; g < 4; ++g)
#pragma unroll
            for (int mt = 0; mt < 2; ++mt) pre[g][mt] = MFMA16(a1h[1][mt], Whi[2][g][1], pre[g][mt]);
#pragma unroll
        for (int g = 0; g < 4; ++g)
#pragma unroll
            for (int mt = 0; mt < 2; ++mt) pre[g][mt] = MFMA16(a1l[0][mt], Whi[2][g][0], pre[g][mt]);
#pragma unroll
        for (int g = 0; g < 4; ++g)
#pragma unroll
            for (int mt = 0; mt < 2; ++mt) pre[g][mt] = MFMA16(a1l[1][mt], Whi[2][g][1], pre[g][mt]);
#pragma unroll
        for (int g = 0; g < 4; ++g)
#pragma unroll
            for (int mt = 0; mt < 2; ++mt) pre[g][mt] = MFMA16(a1h[0][mt], dH[g][0], pre[g][mt]);
#pragma unroll
        for (int g = 0; g < 4; ++g)
#pragma unroll
            for (int mt = 0; mt < 2; ++mt) pre[g][mt] = MFMA16(a1h[1][mt], dH[g][1], pre[g][mt]);

#pragma unroll
        for (int mt = 0; mt < 2; ++mt)
#pragma unroll
            for (int r = 0; r < 4; ++r) {
                const float ig = sigm (pre[0][mt][r]);
                const float fg = sigm (pre[1][mt][r]);
                const float gt = tanh_(pre[2][mt][r]);
                const float og = sigm (pre[3][mt][r]);
                const float c  = fg * c1[mt * 4 + r] + ig * gt;
                c1[mt * 4 + r] = c;
                const float h  = og * tanh_(c);
                const short hb = f2b(h);
                const int  wi  = B1n + (mt * 16 + q * 4 + r) * HSTR + uu;
                Hhi[wi] = hb;
                Hlo[wi] = f2b(h - b2f(hb));
            }
        __syncthreads();   // state visible for next step
    }

    // ================= decoder: 24 autoregressive steps =================
    for (int idx = tid; idx < 2048; idx += 256) {     // re-stage Wchh lo into slot 0
        const int fr = idx;
        const int fcol = fr & 15, fq = (fr >> 4) & 3, fkc = (fr >> 6) & 1;
        const int fg = (fr >> 7) & 3, fw = fr >> 9;
        const float* p = Wchh + (fg * 64 + fw * 16 + fcol) * 64 + fkc * 32 + fq * 8;
        short8 lv;
#pragma unroll
        for (int jj = 0; jj < 8; ++jj) {
            float x = p[jj];
            lv[jj] = f2b(x - b2f(f2b(x)));
        }
        *(short8*)(WloL + fr * 8) = lv;
    }
#pragma unroll
    for (int g = 0; g < 4; ++g)
#pragma unroll
        for (int kc = 0; kc < 2; ++kc)
            hi8(Wchh + (g * 64 + uu) * 64 + kc * 32 + q * 8, Whi[0][g][kc]);
    if (tid < 32) ybufF[tid] = XL[(Lv - 1) * 32 + tid];   // x_cur
    __syncthreads();

    const float boutF = bout[0];
    float* outp = out + b * HZv * Sv + s0;

    for (int t = 0; t < HZv; ++t) {
        const int p = t & 1, np = p ^ 1;
        const int B1p = (2 + p) * HBUF, B1n = (2 + np) * HBUF;

        short8 ah[2][2], al[2][2];
#pragma unroll
        for (int kc = 0; kc < 2; ++kc)
#pragma unroll
            for (int mt = 0; mt < 2; ++mt) {
                const int o = B1p + (mt * 16 + col) * HSTR + kc * 32 + q * 8;
                ah[kc][mt] = *(const short8*)(Hhi + o);
                al[kc][mt] = *(const short8*)(Hlo + o);
            }
        short8 dA[4][2];
#pragma unroll
        for (int g = 0; g < 4; ++g) {
            dA[g][0] = *(const short8*)(WloL + frOff[g][0]);
            dA[g][1] = *(const short8*)(WloL + frOff[g][1]);
        }
        float yv[2][4];
#pragma unroll
        for (int mt = 0; mt < 2; ++mt)
#pragma unroll
            for (int r = 0; r < 4; ++r)
                yv[mt][r] = ybufF[mt * 16 + q * 4 + r];

        f32x4 pre[4][2];
#pragma unroll
        for (int g = 0; g < 4; ++g)
#pragma unroll
            for (int mt = 0; mt < 2; ++mt)
                pre[g][mt] = (f32x4){biasc[g], biasc[g], biasc[g], biasc[g]};
#pragma unroll
        for (int g = 0; g < 4; ++g)
#pragma unroll
            for (int mt = 0; mt < 2; ++mt) pre[g][mt] = MFMA16(ah[0][mt], Whi[0][g][0], pre[g][mt]);
#pragma unroll
        for (int g = 0; g < 4; ++g)
#pragma unroll
            for (int mt = 0; mt < 2; ++mt) pre[g][mt] = MFMA16(ah[1][mt], Whi[0][g][1], pre[g][mt]);
#pragma unroll
        for (int g = 0; g < 4; ++g)
#pragma unroll
            for (int mt = 0; mt < 2; ++mt) pre[g][mt] = MFMA16(al[0][mt], Whi[0][g][0], pre[g][mt]);
#pragma unroll
        for (int g = 0; g < 4; ++g)
#pragma unroll
            for (int mt = 0; mt < 2; ++mt) pre[g][mt] = MFMA16(al[1][mt], Whi[0][g][1], pre[g][mt]);
#pragma unroll
        for (int g = 0; g < 4; ++g)
#pragma unroll
            for (int mt = 0; mt < 2; ++mt) pre[g][mt] = MFMA16(ah[0][mt], dA[g][0], pre[g][mt]);
#pragma unroll
        for (int g = 0; g < 4; ++g)
#pragma unroll
            for (int mt = 0; mt < 2; ++mt) pre[g][mt] = MFMA16(ah[1][mt], dA[g][1], pre[g][mt]);

#pragma unroll
        for (int mt = 0; mt < 2; ++mt)
#pragma unroll
            for (int r = 0; r < 4; ++r) {
                const float xw = yv[mt][r];
                const float ig = sigm (pre[0][mt][r] + xw * wcihg[0]);
                const float fg = sigm (pre[1][mt][r] + xw * wcihg[1]);
                const float gt = tanh_(pre[2][mt][r] + xw * wcihg[2]);
                const float og = sigm (pre[3][mt][r] + xw * wcihg[3]);
                const float c  = fg * c1[mt * 4 + r] + ig * gt;
                c1[mt * 4 + r] = c;
                const float h  = og * tanh_(c);
                const short hb = f2b(h);
                const int  wi  = B1n + (mt * 16 + q * 4 + r) * HSTR + uu;
                Hhi[wi] = hb;
                Hlo[wi] = f2b(h - b2f(hb));
            }
        __syncthreads();   // h(new) visible

        if (tid < 32) {    // y = h @ W_out^T + b_out (exact f32 from hi+lo)
            const int m = tid;
            float s = boutF;
#pragma unroll
            for (int k = 0; k < 64; ++k)
                s += (b2f(Hhi[B1n + m * HSTR + k]) + b2f(Hlo[B1n + m * HSTR + k])) * woutF[k];
            outp[t * Sv + m] = s;
            ybufF[m] = s;
        }
        __syncthreads();
    }
}

extern "C" void kernel_launch(void* const* d_in, const int* in_sizes, int n_in,
                              void* d_out, int out_size, void* d_ws, size_t ws_size,
                              hipStream_t stream)
{
    const float* x_seq = (const float*)d_in[0];
    const float* Wih0  = (const float*)d_in[1];
    const float* Whh0  = (const float*)d_in[2];
    const float* bih0  = (const float*)d_in[3];
    const float* bhh0  = (const float*)d_in[4];
    const float* Wih1  = (const float*)d_in[5];
    const float* Whh1  = (const float*)d_in[6];
    const float* bih1  = (const float*)d_in[7];
    const float* bhh1  = (const float*)d_in[8];
    const float* Wcih  = (const float*)d_in[9];
    const float* Wchh  = (const float*)d_in[10];
    const float* bcih  = (const float*)d_in[11];
    const float* bchh  = (const float*)d_in[12];
    const float* Wout  = (const float*)d_in[13];
    const float* bout  = (const float*)d_in[14];
    float* out = (float*)d_out;

    hipLaunchKernelGGL(sitewise_lstm, dim3(Bv * (Sv / 32)), dim3(256), 0, stream,
                       x_seq, Wih0, Whh0, bih0, bhh0, Wih1, Whh1, bih1, bhh1,
                       Wcih, Wchh, bcih, bchh, Wout, bout, out);
}